// Round 8
// baseline (3275.943 us; speedup 1.0000x reference)
//
#include <hip/hip_runtime.h>

#define NJ  21
#define FT  6
#define TRS 43   // output tile row stride (floats); odd -> bank-conflict-free
#define WRS 12   // weight row stride: 10 floats padded to 12 (48B, 16B-aligned)

// E=2 elements per thread (block covers 512 elements). Rounds 2-7 lesson:
// the wall is the per-element weight-broadcast cost: ~48 ds_read instrs/joint
// /wave at ~12-15cy on ONE LDS pipe per CU shared by 16 waves -> 5x over
// VALU demand -> VALUBusy ~25-30% regardless of write/weight-path variants.
// Fix: each weight ds_read feeds TWO independent element chains (A,B) -> the
// compiler CSEs the LDS reads, halving per-element LDS-pipe demand.

#define F10(W, Bv, a0,a1,a2,a3,a4,a5,a6,a7,a8,a9) \
  fmaxf(fmaf((W)[9],(a9),fmaf((W)[8],(a8),fmaf((W)[7],(a7),fmaf((W)[6],(a6), \
        fmaf((W)[5],(a5),fmaf((W)[4],(a4),fmaf((W)[3],(a3),fmaf((W)[2],(a2), \
        fmaf((W)[1],(a1),fmaf((W)[0],(a0),(Bv))))))))))), 0.0f)

#define HROW2(N,P,j,r) \
  const float hA##N##_##r = F10(w1s + ((j)-1)*10*WRS + (r)*WRS, \
      b1s[((j)-1)*10 + (r)], qA##N.x, qA##N.y, qA##N.z, qA##N.w, \
      fA##P##_0, fA##P##_1, fA##P##_2, fA##P##_3, fA##P##_4, fA##P##_5); \
  const float hB##N##_##r = F10(w1s + ((j)-1)*10*WRS + (r)*WRS, \
      b1s[((j)-1)*10 + (r)], qB##N.x, qB##N.y, qB##N.z, qB##N.w, \
      fB##P##_0, fB##P##_1, fB##P##_2, fB##P##_3, fB##P##_4, fB##P##_5);

#define FROW2(N,j,r) \
  const float fA##N##_##r = F10(w2s + (j)*6*WRS + (r)*WRS, b2s[(j)*6 + (r)], \
      hA##N##_0, hA##N##_1, hA##N##_2, hA##N##_3, hA##N##_4, \
      hA##N##_5, hA##N##_6, hA##N##_7, hA##N##_8, hA##N##_9); \
  const float fB##N##_##r = F10(w2s + (j)*6*WRS + (r)*WRS, b2s[(j)*6 + (r)], \
      hB##N##_0, hB##N##_1, hB##N##_2, hB##N##_3, hB##N##_4, \
      hB##N##_5, hB##N##_6, hB##N##_7, hB##N##_8, hB##N##_9);

#define DO_JOINT(j,P,N) \
  const float4 qA##N = qvA[j]; \
  const float4 qB##N = qvB[j]; \
  HROW2(N,P,j,0) HROW2(N,P,j,1) HROW2(N,P,j,2) HROW2(N,P,j,3) HROW2(N,P,j,4) \
  HROW2(N,P,j,5) HROW2(N,P,j,6) HROW2(N,P,j,7) HROW2(N,P,j,8) HROW2(N,P,j,9) \
  FROW2(N,j,0) FROW2(N,j,1) FROW2(N,j,2) FROW2(N,j,3) FROW2(N,j,4) FROW2(N,j,5)

#define PUT6(p, X) { (p)[0]=f##X##_0; (p)[1]=f##X##_1; (p)[2]=f##X##_2; \
                     (p)[3]=f##X##_3; (p)[4]=f##X##_4; (p)[5]=f##X##_5; }

// Quarter flush: quarter q covers block rows [q*128,(q+1)*128).
// q=0,1: element set A (threads 0-127 / 128-255); q=2,3: element set B.
#define QFLUSH(k, q, EL, N0,N1,N2,N3,N4,N5,N6) \
  __syncthreads(); \
  if ((tid >> 7) == ((q) & 1)) { \
    float* tr_ = tile + (tid & 127) * TRS; \
    PUT6(tr_+0,  EL##N0) PUT6(tr_+6,  EL##N1) PUT6(tr_+12, EL##N2) \
    PUT6(tr_+18, EL##N3) PUT6(tr_+24, EL##N4) PUT6(tr_+30, EL##N5) \
    PUT6(tr_+36, EL##N6) \
  } \
  __syncthreads(); \
  { const int lane_ = tid & 63, w_ = tid >> 6; \
    _Pragma("unroll") \
    for (int i_ = 0; i_ < 21; ++i_) { \
      const int idx_ = w_ * 1344 + i_ * 64 + lane_; \
      const int row_ = idx_ / 42, col_ = idx_ - row_ * 42; \
      const int rg_  = base + (q)*128 + row_; \
      if (rg_ < B) out[(size_t)rg_ * 126 + (k)*42 + col_] = tile[row_ * TRS + col_]; \
    } \
  }

#define CHUNK_FLUSH(k, N0,N1,N2,N3,N4,N5,N6) \
  QFLUSH(k, 0, A, N0,N1,N2,N3,N4,N5,N6) \
  QFLUSH(k, 1, A, N0,N1,N2,N3,N4,N5,N6) \
  QFLUSH(k, 2, B, N0,N1,N2,N3,N4,N5,N6) \
  QFLUSH(k, 3, B, N0,N1,N2,N3,N4,N5,N6)

__global__ __launch_bounds__(256, 4) void se_kernel(
    const float* __restrict__ quat,   // [B, 21, 4]
    const float* __restrict__ W1r,    // [10, 4]
    const float* __restrict__ b1r,    // [10]
    const float* __restrict__ W1,     // [20, 10, 10]
    const float* __restrict__ b1,     // [20, 10]
    const float* __restrict__ W2,     // [21, 6, 10]
    const float* __restrict__ b2,     // [21, 6]
    float*       __restrict__ out,    // [B, 126]
    int B)
{
    __shared__ __align__(16) float w1s[20*10*WRS];   // 9600 B
    __shared__ __align__(16) float w2s[21*6*WRS];    // 6048 B
    __shared__ float b1s[200], b2s[126], w1rs[40], b1rs[16];
    __shared__ float tile[128*TRS];                  // 22016 B -> ~38.3 KB total

    const int tid  = threadIdx.x;
    const int base = blockIdx.x * 512;               // block covers 512 elements

    for (int i = tid; i < 2000; i += 256) w1s[(i/10)*WRS + i%10] = W1[i];
    for (int i = tid; i < 1260; i += 256) w2s[(i/10)*WRS + i%10] = W2[i];
    for (int i = tid; i < 200;  i += 256) b1s[i] = b1[i];
    if (tid < 126) b2s[tid] = b2[tid];
    if (tid < 40)  w1rs[tid] = W1r[tid];
    if (tid < 10)  b1rs[tid] = b1r[tid];
    __syncthreads();

    const int eA = min(base + tid,       B - 1);
    const int eB = min(base + tid + 256, B - 1);
    const float4* __restrict__ qvA =
        reinterpret_cast<const float4*>(quat) + (size_t)eA * NJ;
    const float4* __restrict__ qvB =
        reinterpret_cast<const float4*>(quat) + (size_t)eB * NJ;

    // ---- chunk 0: joints 0..6 ----
    const float4 qA0 = qvA[0];
    const float4 qB0 = qvB[0];
#define H0ROW2(r) \
    const float hA0_##r = fmaxf( \
      fmaf(w1rs[(r)*4+3], qA0.w, fmaf(w1rs[(r)*4+2], qA0.z, \
      fmaf(w1rs[(r)*4+1], qA0.y, fmaf(w1rs[(r)*4+0], qA0.x, b1rs[r])))), 0.0f); \
    const float hB0_##r = fmaxf( \
      fmaf(w1rs[(r)*4+3], qB0.w, fmaf(w1rs[(r)*4+2], qB0.z, \
      fmaf(w1rs[(r)*4+1], qB0.y, fmaf(w1rs[(r)*4+0], qB0.x, b1rs[r])))), 0.0f);
    H0ROW2(0) H0ROW2(1) H0ROW2(2) H0ROW2(3) H0ROW2(4)
    H0ROW2(5) H0ROW2(6) H0ROW2(7) H0ROW2(8) H0ROW2(9)
#undef H0ROW2
    FROW2(0,0,0) FROW2(0,0,1) FROW2(0,0,2) FROW2(0,0,3) FROW2(0,0,4) FROW2(0,0,5)

    DO_JOINT(1,0,1)  DO_JOINT(2,0,2)  DO_JOINT(3,0,3)
    DO_JOINT(4,1,4)  DO_JOINT(5,2,5)  DO_JOINT(6,3,6)
    CHUNK_FLUSH(0, 0,1,2,3,4,5,6)

    // ---- chunk 1: joints 7..13 ----
    DO_JOINT(7,4,7)   DO_JOINT(8,5,8)   DO_JOINT(9,6,9)
    DO_JOINT(10,7,10) DO_JOINT(11,8,11)
    DO_JOINT(12,9,12) DO_JOINT(13,9,13)
    CHUNK_FLUSH(1, 7,8,9,10,11,12,13)

    // ---- chunk 2: joints 14..20 ----
    DO_JOINT(14,9,14)  DO_JOINT(15,12,15) DO_JOINT(16,13,16)
    DO_JOINT(17,14,17) DO_JOINT(18,16,18)
    DO_JOINT(19,17,19) DO_JOINT(20,18,20)
    CHUNK_FLUSH(2, 14,15,16,17,18,19,20)
}

extern "C" void kernel_launch(void* const* d_in, const int* in_sizes, int n_in,
                              void* d_out, int out_size, void* d_ws, size_t ws_size,
                              hipStream_t stream) {
    const float* quat = (const float*)d_in[0];
    const float* W1r  = (const float*)d_in[1];
    const float* b1r  = (const float*)d_in[2];
    const float* W1   = (const float*)d_in[3];
    const float* b1   = (const float*)d_in[4];
    const float* W2   = (const float*)d_in[5];
    const float* b2   = (const float*)d_in[6];
    float* out = (float*)d_out;

    const int B = in_sizes[0] / (NJ * 4);
    const int blocks = (B + 511) / 512;
    se_kernel<<<blocks, 256, 0, stream>>>(quat, W1r, b1r, W1, b1, W2, b2, out, B);
}